// Round 1
// baseline (140.766 us; speedup 1.0000x reference)
//
#include <hip/hip_runtime.h>

// flex_conv: out[b,o,i,j] = sum_{d,ic,k,f} rel[b,d,i,j,k,f] * x[b,ic,i+k,j+f] * K[o,ic,d]
// rel[d<3] = ctr[d] - pts[d, i+k, j+f],  rel[3] = 1,  ctr[d] = pts[d, i+1, j+1]
// Factored: per (pixel, ic): Xs = box3x3(x), PXd = box3x3(pts_d * x)
//           t_d = ctr_d*Xs - PXd (d<3), t_3 = Xs
//           out[o] = sum_ic sum_d K[o,ic,d] * t[ic,d]

#define KSZ 3
#define HH 64
#define WW 512
#define HP 62
#define WP 510
#define IC 16
#define OC 32
#define BS 16

__global__ __launch_bounds__(256) void flex_conv_kernel(
    const float* __restrict__ x,
    const float* __restrict__ kern,
    const float* __restrict__ pts,
    float* __restrict__ out)
{
    const int j = blockIdx.x * blockDim.x + threadIdx.x;
    const int i = blockIdx.y;
    const int b = blockIdx.z;
    if (j >= WP) return;

    // Load the 3x3 points window for the 3 coordinate channels.
    float p0[9], p1[9], p2[9];
    const float* pb = pts + (size_t)b * 3 * HH * WW;
    #pragma unroll
    for (int k = 0; k < KSZ; ++k) {
        #pragma unroll
        for (int f = 0; f < KSZ; ++f) {
            const int e = k * KSZ + f;
            const size_t off = (size_t)(i + k) * WW + (j + f);
            p0[e] = pb[0 * (size_t)HH * WW + off];
            p1[e] = pb[1 * (size_t)HH * WW + off];
            p2[e] = pb[2 * (size_t)HH * WW + off];
        }
    }
    // Center = middle element of the window (bd=1, st=1).
    const float c0 = p0[4], c1 = p1[4], c2 = p2[4];

    float acc[OC];
    #pragma unroll
    for (int o = 0; o < OC; ++o) acc[o] = 0.0f;

    const float* xb = x + (size_t)b * IC * HH * WW;
    for (int ic = 0; ic < IC; ++ic) {
        float xs = 0.0f, px0 = 0.0f, px1 = 0.0f, px2 = 0.0f;
        const float* xc = xb + (size_t)ic * HH * WW + (size_t)i * WW + j;
        #pragma unroll
        for (int k = 0; k < KSZ; ++k) {
            #pragma unroll
            for (int f = 0; f < KSZ; ++f) {
                const float xv = xc[(size_t)k * WW + f];
                const int e = k * KSZ + f;
                xs += xv;
                px0 = fmaf(p0[e], xv, px0);
                px1 = fmaf(p1[e], xv, px1);
                px2 = fmaf(p2[e], xv, px2);
            }
        }
        const float t0 = fmaf(c0, xs, -px0);
        const float t1 = fmaf(c1, xs, -px1);
        const float t2 = fmaf(c2, xs, -px2);
        const float t3 = xs;

        // kern layout: [o][ic][d], d fastest. Indices are thread-uniform ->
        // compiler should emit scalar loads (SGPR operands in the FMAs).
        const float* kk = kern + ic * 4;
        #pragma unroll
        for (int o = 0; o < OC; ++o) {
            const float* ko = kk + (size_t)o * IC * 4;
            float a = acc[o];
            a = fmaf(ko[0], t0, a);
            a = fmaf(ko[1], t1, a);
            a = fmaf(ko[2], t2, a);
            a = fmaf(ko[3], t3, a);
            acc[o] = a;
        }
    }

    float* ob = out + (size_t)b * OC * HP * WP + (size_t)i * WP + j;
    #pragma unroll
    for (int o = 0; o < OC; ++o) {
        ob[(size_t)o * HP * WP] = acc[o];
    }
}

extern "C" void kernel_launch(void* const* d_in, const int* in_sizes, int n_in,
                              void* d_out, int out_size, void* d_ws, size_t ws_size,
                              hipStream_t stream)
{
    const float* x    = (const float*)d_in[0];
    const float* kern = (const float*)d_in[1];
    const float* pts  = (const float*)d_in[2];
    float* out = (float*)d_out;

    dim3 block(256, 1, 1);
    dim3 grid((WP + 255) / 256, HP, BS);
    flex_conv_kernel<<<grid, block, 0, stream>>>(x, kern, pts, out);
}